// Round 11
// baseline (380.579 us; speedup 1.0000x reference)
//
#include <hip/hip_runtime.h>

#define EPROJS 1024
#define DUNITS 1024
#define AHEADS 4
#define DK 512
#define DV 512
#define CCH 128
#define BB 16
#define TT 2048

typedef __attribute__((ext_vector_type(8))) short bf16x8;
typedef __attribute__((ext_vector_type(4))) float f32x4;

#define GLL16(gsrc, ldst)                                                        \
  __builtin_amdgcn_global_load_lds(                                              \
      (const __attribute__((address_space(1))) void*)(gsrc),                     \
      (__attribute__((address_space(3))) void*)(ldst), 16, 0, 0)

static __device__ __forceinline__ short f2bf(float x) {
  unsigned u = __float_as_uint(x);
  unsigned r = u + 0x7fffu + ((u >> 16) & 1u);   // RNE to bf16 (inputs finite)
  return (short)(r >> 16);
}
static __device__ __forceinline__ float bf2f(short x) {
  return __uint_as_float(((unsigned)(unsigned short)x) << 16);
}
static __device__ __forceinline__ float fast_tanh(float x) {
  float e2 = __expf(2.0f * x);
  return 1.0f - 2.0f / (e2 + 1.0f);
}

// ---------- fused prep: cvt enc, packB, prefix sums, Q, zero ctx ----------
__global__ __launch_bounds__(256) void prep_kernel(
    const float* __restrict__ enc, short* __restrict__ encb,
    const float* __restrict__ Wk, const float* __restrict__ Watt, short* __restrict__ Bp,
    const float* __restrict__ w0, const float* __restrict__ w1,
    const float* __restrict__ w2, const float* __restrict__ w3, float* __restrict__ S,
    const float* __restrict__ dec, const float* __restrict__ Wq,
    const float* __restrict__ bq, float* __restrict__ Qb,
    float* __restrict__ ctx) {
  int bid = blockIdx.x, tid = threadIdx.x;
  if (bid < 32768) {
    // enc f32 -> bf16
    int i = bid * 256 + tid;
    float4 v = reinterpret_cast<const float4*>(enc)[i];
    short4 o;
    o.x = f2bf(v.x); o.y = f2bf(v.y); o.z = f2bf(v.z); o.w = f2bf(v.w);
    reinterpret_cast<short4*>(encb)[i] = o;
  } else if (bid < 33920) {
    // pack B = [Wk | Watt] into MFMA fragment order
    int idx = (bid - 32768) * 256 + tid;
    int lane = idx & 63; int t = idx >> 6;
    int nblk = t & 31; t >>= 5;
    int kkidx = t % 36; int h = t / 36;
    int col = nblk * 16 + (lane & 15);
    int k0 = kkidx * 32 + (lane >> 4) * 8;
    const float* src;
    if (k0 < 1024) src = Wk + ((size_t)(h * DK + col)) * EPROJS + k0;
    else           src = Watt + ((size_t)(h * DK + col)) * CCH + (k0 - 1024);
    float4 v0 = reinterpret_cast<const float4*>(src)[0];
    float4 v1 = reinterpret_cast<const float4*>(src)[1];
    short o[8] = { f2bf(v0.x), f2bf(v0.y), f2bf(v0.z), f2bf(v0.w),
                   f2bf(v1.x), f2bf(v1.y), f2bf(v1.z), f2bf(v1.w) };
    *reinterpret_cast<bf16x8*>(Bp + (size_t)idx * 8) = *reinterpret_cast<bf16x8*>(o);
  } else if (bid < 33924) {
    // filter prefix sums
    if (tid < 128) {
      int h = bid - 33920, c = tid;
      const float* wk = (h == 0) ? w0 : (h == 1) ? w1 : (h == 2) ? w2 : w3;
      int af = (100 * (h + 1)) >> 2;
      int L = 2 * af + 1;
      float* Sh = S + h * 202 * 128;
      float s = 0.f;
      Sh[c] = 0.f;
      for (int t = 0; t < L; ++t) { s += wk[c * L + t]; Sh[(t + 1) * 128 + c] = s; }
    }
  } else if (bid < 42116) {
    // Q[h][b][k]
    int wid = ((bid - 33924) * 256 + tid) >> 6;
    int lane = tid & 63;
    int k = wid & (DK - 1); int hb = wid >> 9; int b = hb & (BB - 1); int h = hb >> 4;
    const float4* d4 = reinterpret_cast<const float4*>(dec + b * DUNITS);
    const float4* w4 = reinterpret_cast<const float4*>(Wq + (size_t)(h * DK + k) * DUNITS);
    float s = 0.f;
#pragma unroll
    for (int j = 0; j < 4; ++j) {
      float4 a = d4[j * 64 + lane], w = w4[j * 64 + lane];
      s += a.x * w.x + a.y * w.y + a.z * w.z + a.w * w.w;
    }
#pragma unroll
    for (int off = 32; off; off >>= 1) s += __shfl_xor(s, off);
    if (lane == 0) Qb[wid] = s + bq[h * DK + k];
  } else {
    int i = (bid - 42116) * 256 + tid;
    if (i < 65536) ctx[i] = 0.f;
  }
}

// ---------- fused e kernel ----------
// Tri-buffered LDS staging via global_load_lds; counted vmcnt before each barrier.
// Main loop t=0..7 branch-free: B prefetch via single uint32 offset bump (trailing
// prefetches read in-bounds ws garbage, never consumed). Tile 8 (conv) peeled.
__global__ __launch_bounds__(512, 3) void e_kernel(const short* __restrict__ encb,
                                                   const short* __restrict__ Bp,
                                                   const float* __restrict__ S,
                                                   const float* __restrict__ Qb,
                                                   const float* __restrict__ gw,
                                                   const int* __restrict__ lens,
                                                   float* __restrict__ ebuf) {
  __shared__ short At[3][64 * 128];
  __shared__ float epart[8][64];

  int bid = blockIdx.x;
  int h = bid >> 9; int rem = bid & 511; int b = rem >> 5; int t0 = (rem & 31) << 6;
  int tid = threadIdx.x; int w = tid >> 6; int l = tid & 63;
  int lrow = l & 15, lhi = l >> 4;
  int len = lens[b];
  float invlen = 1.0f / (float)len;
  int af = (100 * (h + 1)) >> 2;

  const short* encB = encb + ((size_t)(b * TT + t0)) * EPROJS;
  const short* BpL = Bp + (size_t)h * 589824 + (w * 4) * 512 + l * 8;

  // staging addresses: 2 chunks/thread, LDS chunk-linear (lane-contiguous per wave)
  int ci0 = tid, ci1 = 512 + tid;
  int r0 = ci0 >> 4, p0 = ci0 & 15;
  int r1 = ci1 >> 4, p1 = ci1 & 15;
  const short* g0 = encB + (size_t)r0 * EPROJS + ((p0 ^ (r0 & 7)) << 3);
  const short* g1 = encB + (size_t)r1 * EPROJS + ((p1 ^ (r1 & 7)) << 3);
  int d0 = ci0 * 8, d1 = ci1 * 8;   // LDS offsets in shorts
  int rx = lrow & 7;

  // B depth-1 prefetch: kkidx 0
  bf16x8 bnext[4];
#pragma unroll
  for (int n = 0; n < 4; ++n)
    bnext[n] = *reinterpret_cast<const bf16x8*>(BpL + n * 512);
  unsigned boff = 16384;   // next prefetch offset (shorts): kkidx 1

  short* A0 = &At[0][0]; short* A1 = &At[1][0]; short* A2 = &At[2][0];

  // stage tiles 0 (buf0) and 1 (buf1)
  GLL16(g0, A0 + d0); GLL16(g1, A0 + d1);
  GLL16(g0 + 128, A1 + d0); GLL16(g1 + 128, A1 + d1);

  f32x4 acc[4][4] = {};

  __builtin_amdgcn_sched_barrier(0);
  asm volatile("s_waitcnt vmcnt(2)" ::: "memory");   // tile 0 complete; tile 1 in flight
  __builtin_amdgcn_s_barrier();
  __builtin_amdgcn_sched_barrier(0);

  const float* Sh = S + h * 202 * 128;

  for (int t = 0; t < 8; ++t) {
    if (t == 6) {
      // conv tile (tile 8) into buf2 == A2 at this rotation
      int srow = tid >> 3, sc = tid & 7;
      int tt = t0 + srow;
      int lo = af - tt; if (lo < 0) lo = 0;
      int hi = af - tt + len - 1; if (hi > 2 * af) hi = 2 * af;
      bool any = (hi >= lo);
      const float* Plo = Sh + lo * 128;
      const float* Phi = Sh + (hi + 1) * 128;
      short o0[8], o1[8];
#pragma unroll
      for (int e = 0; e < 8; ++e) {
        int c = sc * 8 + e;
        float v0 = any ? (Phi[c] - Plo[c]) * invlen : 0.f;
        float v1 = any ? (Phi[c + 64] - Plo[c + 64]) * invlen : 0.f;
        o0[e] = f2bf(v0); o1[e] = f2bf(v1);
      }
      *reinterpret_cast<bf16x8*>(&A2[srow * 128 + ((sc ^ (srow & 7)) << 3)]) =
          *reinterpret_cast<bf16x8*>(o0);
      *reinterpret_cast<bf16x8*>(&A2[srow * 128 + (((sc + 8) ^ (srow & 7)) << 3)]) =
          *reinterpret_cast<bf16x8*>(o1);
    }
#pragma unroll
    for (int kk = 0; kk < 4; ++kk) {
      bf16x8 bcur[4];
#pragma unroll
      for (int n = 0; n < 4; ++n) bcur[n] = bnext[n];
      // branch-free prefetch: offset bump, offsets n*1024B fold into imm
#pragma unroll
      for (int n = 0; n < 4; ++n)
        bnext[n] = *reinterpret_cast<const bf16x8*>(BpL + boff + n * 512);
      boff += 16384;
      bf16x8 afr[4];
      int x = ((kk * 4 + lhi) ^ rx) << 3;
#pragma unroll
      for (int m = 0; m < 4; ++m)
        afr[m] = *reinterpret_cast<const bf16x8*>(&A0[(m * 16 + lrow) * 128 + x]);
#pragma unroll
      for (int m = 0; m < 4; ++m)
#pragma unroll
        for (int n = 0; n < 4; ++n)
          acc[m][n] = __builtin_amdgcn_mfma_f32_16x16x32_bf16(afr[m], bcur[n], acc[m][n], 0, 0, 0);
    }
    if (t < 6) {
      // stage tile t+2 into A2 (freed after iter t-1); issued AFTER this iter's B loads
      __builtin_amdgcn_sched_barrier(0);
      const short* gs0 = g0 + (t + 2) * 128;
      const short* gs1 = g1 + (t + 2) * 128;
      GLL16(gs0, A2 + d0); GLL16(gs1, A2 + d1);
    }
    __builtin_amdgcn_sched_barrier(0);
    if (t < 6) {
      // allow: 4 B-prefetch (kk=3) + 2 staging(t+2); forces staging(t+1) complete
      asm volatile("s_waitcnt vmcnt(6) lgkmcnt(0)" ::: "memory");
    } else {
      // no staging issued this iter; allow only the 4 B-prefetch loads
      asm volatile("s_waitcnt vmcnt(4) lgkmcnt(0)" ::: "memory");
    }
    __builtin_amdgcn_s_barrier();
    __builtin_amdgcn_sched_barrier(0);
    // rotate buffers: read buf advances
    short* tmp = A0; A0 = A1; A1 = A2; A2 = tmp;
  }

  // peeled tile 8 (conv, kkidx 32..35) — consumes from A0; no barrier needed after
#pragma unroll
  for (int kk = 0; kk < 4; ++kk) {
    bf16x8 bcur[4];
#pragma unroll
    for (int n = 0; n < 4; ++n) bcur[n] = bnext[n];
#pragma unroll
    for (int n = 0; n < 4; ++n)
      bnext[n] = *reinterpret_cast<const bf16x8*>(BpL + boff + n * 512);  // tail garbage, unused at kk=3
    boff += 16384;
    bf16x8 afr[4];
    int x = ((kk * 4 + lhi) ^ rx) << 3;
#pragma unroll
    for (int m = 0; m < 4; ++m)
      afr[m] = *reinterpret_cast<const bf16x8*>(&A0[(m * 16 + lrow) * 128 + x]);
#pragma unroll
    for (int m = 0; m < 4; ++m)
#pragma unroll
      for (int n = 0; n < 4; ++n)
        acc[m][n] = __builtin_amdgcn_mfma_f32_16x16x32_bf16(afr[m], bcur[n], acc[m][n], 0, 0, 0);
  }

  // epilogue: tanh(pre + Q) * g_w, reduce over k
  float part[4][4];
#pragma unroll
  for (int m = 0; m < 4; ++m)
#pragma unroll
    for (int r = 0; r < 4; ++r) part[m][r] = 0.f;

#pragma unroll
  for (int n = 0; n < 4; ++n) {
    int col = w * 64 + n * 16 + lrow;
    float qv = Qb[(h * BB + b) * DK + col];
    float gv = gw[h * DK + col];
#pragma unroll
    for (int m = 0; m < 4; ++m)
#pragma unroll
      for (int r = 0; r < 4; ++r)
        part[m][r] += fast_tanh(acc[m][n][r] + qv) * gv;
  }
#pragma unroll
  for (int off = 1; off < 16; off <<= 1)
#pragma unroll
    for (int m = 0; m < 4; ++m)
#pragma unroll
      for (int r = 0; r < 4; ++r) part[m][r] += __shfl_xor(part[m][r], off);

  if (lrow == 0) {
#pragma unroll
    for (int m = 0; m < 4; ++m)
#pragma unroll
      for (int r = 0; r < 4; ++r) epart[w][m * 16 + lhi * 4 + r] = part[m][r];
  }
  __syncthreads();
  if (tid < 64) {
    float s = 0.f;
#pragma unroll
    for (int ww = 0; ww < 8; ++ww) s += epart[ww][tid];
    ebuf[(size_t)(h * BB + b) * TT + t0 + tid] = s;
  }
}

// ---------- masked softmax over t; writes ws region of d_out ----------
__global__ __launch_bounds__(256) void softmax_kernel(const float* __restrict__ ebuf,
                                                      const int* __restrict__ lens,
                                                      float* __restrict__ wout) {
  int hb = blockIdx.x; int b = hb & (BB - 1);
  int tid = threadIdx.x;
  int len = lens[b];
  const float scaling = 0.04419417382415922f;  // 1/sqrt(512)
  const float* er = ebuf + (size_t)hb * TT;
  float vals[8];
  float mx = -1e30f;
#pragma unroll
  for (int j = 0; j < 8; ++j) {
    int t = j * 256 + tid;
    float v = (t < len) ? scaling * er[t] : -1e30f;
    vals[j] = v; mx = fmaxf(mx, v);
  }
  __shared__ float red[256];
  red[tid] = mx; __syncthreads();
  for (int s2 = 128; s2; s2 >>= 1) { if (tid < s2) red[tid] = fmaxf(red[tid], red[tid + s2]); __syncthreads(); }
  mx = red[0]; __syncthreads();
  float sum = 0.f;
#pragma unroll
  for (int j = 0; j < 8; ++j) {
    int t = j * 256 + tid;
    vals[j] = (t < len) ? __expf(vals[j] - mx) : 0.f;
    sum += vals[j];
  }
  red[tid] = sum; __syncthreads();
  for (int s2 = 128; s2; s2 >>= 1) { if (tid < s2) red[tid] += red[tid + s2]; __syncthreads(); }
  float inv = 1.f / red[0];
#pragma unroll
  for (int j = 0; j < 8; ++j)
    wout[(size_t)hb * TT + j * 256 + tid] = vals[j] * inv;
}

// ---------- ctx[h][b][e] = sum_t w[h][b][t] * enc_bf16[b][t][e] ----------
// block (b16, tc32) over 64 t-rows; thread owns 4 e-cols -> short4 coalesced loads.
__global__ __launch_bounds__(256) void ctx_kernel(const short* __restrict__ encb,
                                                  const float* __restrict__ wout,
                                                  float* __restrict__ ctx) {
  int bid = blockIdx.x;                      // 512 = b(16) x tc(32)
  int tc = bid & 31; int b = bid >> 5;
  int t0 = tc * 64;
  int tid = threadIdx.x;                     // cols tid*4 .. tid*4+3
  __shared__ float wls[4][64];
  if (tid < 64) {
#pragma unroll
    for (int h = 0; h < 4; ++h) wls[h][tid] = wout[(size_t)(h * BB + b) * TT + t0 + tid];
  }
  __syncthreads();
  float a[4][4] = {};
  const short* ep = encb + ((size_t)(b * TT + t0)) * EPROJS + tid * 4;
  for (int t2 = 0; t2 < 64; ++t2) {
    short4 v = *reinterpret_cast<const short4*>(ep + (size_t)t2 * EPROJS);
    float f0 = bf2f(v.x), f1 = bf2f(v.y), f2 = bf2f(v.z), f3 = bf2f(v.w);
#pragma unroll
    for (int h = 0; h < 4; ++h) {
      float wv = wls[h][t2];
      a[h][0] += wv * f0; a[h][1] += wv * f1; a[h][2] += wv * f2; a[h][3] += wv * f3;
    }
  }
#pragma unroll
  for (int h = 0; h < 4; ++h)
#pragma unroll
    for (int e = 0; e < 4; ++e)
      atomicAdd(&ctx[(h * BB + b) * EPROJS + tid * 4 + e], a[h][e]);
}

// ---------- cv[b][h*512+v] = ctx[h][b] . Wv[h][v] ; one wave per (h,v), all 16 b ----------
__global__ __launch_bounds__(256) void cv_kernel(const float* __restrict__ ctx,
                                                 const float* __restrict__ Wv,
                                                 float* __restrict__ cvb) {
  int wid = (blockIdx.x * blockDim.x + threadIdx.x) >> 6;   // 0..2047
  int lane = threadIdx.x & 63;
  int v = wid & (DV - 1); int h = wid >> 9;
  const float4* w4 = reinterpret_cast<const float4*>(Wv + (size_t)(h * DV + v) * EPROJS);
  float acc[BB];
#pragma unroll
  for (int b = 0; b < BB; ++b) acc[b] = 0.f;
#pragma unroll
  for (int j = 0; j < 4; ++j) {
    float4 ww = w4[j * 64 + lane];
#pragma unroll
    for (int b = 0; b < BB; ++b) {
      float4 a = reinterpret_cast<const float4*>(ctx + (size_t)(h * BB + b) * EPROJS)[j * 64 + lane];
      acc[b] += a.x * ww.x + a.y * ww.y + a.z * ww.z + a.w * ww.w;
    }
  }
#pragma unroll
  for (int off = 32; off; off >>= 1)
#pragma unroll
    for (int b = 0; b < BB; ++b) acc[b] += __shfl_xor(acc[b], off);
  if (lane == 0) {
#pragma unroll
    for (int b = 0; b < BB; ++b) cvb[b * 2048 + h * DV + v] = acc[b];
  }
}

// ---------- c[b][p] = cv[b] . Wo[p] ; one wave per p, all 16 b ----------
__global__ __launch_bounds__(256) void out_kernel(const float* __restrict__ cvb,
                                                  const float* __restrict__ Wo,
                                                  float* __restrict__ outc) {
  int p = (blockIdx.x * blockDim.x + threadIdx.x) >> 6;   // 0..1023
  int lane = threadIdx.x & 63;
  const float4* w4 = reinterpret_cast<const float4*>(Wo + (size_t)p * 2048);
  float acc[BB];
#pragma unroll
  for (int b = 0; b < BB; ++b) acc[b] = 0.f;
#pragma unroll
  for (int j = 0; j < 8; ++j) {
    float4 ww = w4[j * 64 + lane];
#pragma unroll
    for (int b = 0; b < BB; ++b) {
      float4 a = reinterpret_cast<const float4*>(cvb + (size_t)b * 2048)[j * 64 + lane];
      acc[b] += a.x * ww.x + a.y * ww.y + a.z * ww.z + a.w * ww.w;
    }
  }
#pragma unroll
  for (int off = 32; off; off >>= 1)
#pragma unroll
    for (int b = 0; b < BB; ++b) acc[b] += __shfl_xor(acc[b], off);
  if (lane == 0) {
#pragma unroll
    for (int b = 0; b < BB; ++b) outc[b * 1024 + p] = acc[b];
  }
}

extern "C" void kernel_launch(void* const* d_in, const int* in_sizes, int n_in,
                              void* d_out, int out_size, void* d_ws, size_t ws_size,
                              hipStream_t stream) {
  const float* enc  = (const float*)d_in[0];
  const int*   lens = (const int*)d_in[1];
  const float* dec  = (const float*)d_in[2];
  const float* Wq   = (const float*)d_in[3];
  const float* bq   = (const float*)d_in[4];
  const float* Wk   = (const float*)d_in[5];
  const float* Wv   = (const float*)d_in[6];
  const float* gw   = (const float*)d_in[7];
  const float* Watt = (const float*)d_in[9];
  const float* cw0  = (const float*)d_in[10];
  const float* cw1  = (const float*)d_in[11];
  const float* cw2  = (const float*)d_in[12];
  const float* cw3  = (const float*)d_in[13];
  const float* Wo   = (const float*)d_in[14];
  float* out = (float*)d_out;

  char* ws = (char*)d_ws;
  short* Bp    = (short*)(ws);                 // 4,718,592 B
  float* S     = (float*)(ws + 4718592);       // 413,696 B
  float* Qb    = (float*)(ws + 5132288);       // 131,072 B
  float* ebuf  = (float*)(ws + 5263360);       // 524,288 B
  float* ctx   = (float*)(ws + 6311936);       // 262,144 B
  float* cvb   = (float*)(ws + 6574080);       // 131,072 B
  short* encb  = (short*)(ws + 6815744);       // 67,108,864 B

  float* wsout = out + 16384;                  // ws output region (4,16,2048)

  prep_kernel<<<42372, 256, 0, stream>>>(enc, encb, Wk, Watt, Bp,
                                         cw0, cw1, cw2, cw3, S,
                                         dec, Wq, bq, Qb, ctx);
  e_kernel<<<2048, 512, 0, stream>>>(encb, Bp, S, Qb, gw, lens, ebuf);
  softmax_kernel<<<64, 256, 0, stream>>>(ebuf, lens, wsout);
  ctx_kernel<<<512, 256, 0, stream>>>(encb, wsout, ctx);
  cv_kernel<<<512, 256, 0, stream>>>(ctx, Wv, cvb);
  out_kernel<<<256, 256, 0, stream>>>(cvb, Wo, out);
}

// Round 12
// 311.581 us; speedup vs baseline: 1.2214x; 1.2214x over previous
//
#include <hip/hip_runtime.h>

#define EPROJS 1024
#define DUNITS 1024
#define AHEADS 4
#define DK 512
#define DV 512
#define CCH 128
#define BB 16
#define TT 2048

typedef __attribute__((ext_vector_type(8))) short bf16x8;
typedef __attribute__((ext_vector_type(4))) float f32x4;

#define GLL16(gsrc, ldst)                                                        \
  __builtin_amdgcn_global_load_lds(                                              \
      (const __attribute__((address_space(1))) void*)(gsrc),                     \
      (__attribute__((address_space(3))) void*)(ldst), 16, 0, 0)

static __device__ __forceinline__ short f2bf(float x) {
  unsigned u = __float_as_uint(x);
  unsigned r = u + 0x7fffu + ((u >> 16) & 1u);   // RNE to bf16 (inputs finite)
  return (short)(r >> 16);
}
static __device__ __forceinline__ float bf2f(short x) {
  return __uint_as_float(((unsigned)(unsigned short)x) << 16);
}
static __device__ __forceinline__ float fast_tanh(float x) {
  float e2 = __expf(2.0f * x);
  return 1.0f - 2.0f / (e2 + 1.0f);
}

// ---------- fused prep: cvt enc, packB, prefix sums, Q, zero ctx ----------
__global__ __launch_bounds__(256) void prep_kernel(
    const float* __restrict__ enc, short* __restrict__ encb,
    const float* __restrict__ Wk, const float* __restrict__ Watt, short* __restrict__ Bp,
    const float* __restrict__ w0, const float* __restrict__ w1,
    const float* __restrict__ w2, const float* __restrict__ w3, float* __restrict__ S,
    const float* __restrict__ dec, const float* __restrict__ Wq,
    const float* __restrict__ bq, float* __restrict__ Qb,
    float* __restrict__ ctx) {
  int bid = blockIdx.x, tid = threadIdx.x;
  if (bid < 32768) {
    // enc f32 -> bf16
    int i = bid * 256 + tid;
    float4 v = reinterpret_cast<const float4*>(enc)[i];
    short4 o;
    o.x = f2bf(v.x); o.y = f2bf(v.y); o.z = f2bf(v.z); o.w = f2bf(v.w);
    reinterpret_cast<short4*>(encb)[i] = o;
  } else if (bid < 33920) {
    // pack B = [Wk | Watt] into MFMA fragment order
    int idx = (bid - 32768) * 256 + tid;
    int lane = idx & 63; int t = idx >> 6;
    int nblk = t & 31; t >>= 5;
    int kkidx = t % 36; int h = t / 36;
    int col = nblk * 16 + (lane & 15);
    int k0 = kkidx * 32 + (lane >> 4) * 8;
    const float* src;
    if (k0 < 1024) src = Wk + ((size_t)(h * DK + col)) * EPROJS + k0;
    else           src = Watt + ((size_t)(h * DK + col)) * CCH + (k0 - 1024);
    float4 v0 = reinterpret_cast<const float4*>(src)[0];
    float4 v1 = reinterpret_cast<const float4*>(src)[1];
    short o[8] = { f2bf(v0.x), f2bf(v0.y), f2bf(v0.z), f2bf(v0.w),
                   f2bf(v1.x), f2bf(v1.y), f2bf(v1.z), f2bf(v1.w) };
    *reinterpret_cast<bf16x8*>(Bp + (size_t)idx * 8) = *reinterpret_cast<bf16x8*>(o);
  } else if (bid < 33924) {
    // filter prefix sums
    if (tid < 128) {
      int h = bid - 33920, c = tid;
      const float* wk = (h == 0) ? w0 : (h == 1) ? w1 : (h == 2) ? w2 : w3;
      int af = (100 * (h + 1)) >> 2;
      int L = 2 * af + 1;
      float* Sh = S + h * 202 * 128;
      float s = 0.f;
      Sh[c] = 0.f;
      for (int t = 0; t < L; ++t) { s += wk[c * L + t]; Sh[(t + 1) * 128 + c] = s; }
    }
  } else if (bid < 34436) {
    // Q[h][b][k]: one wave per (h,k), ALL 16 b -> Wq row read exactly once
    int wid = ((bid - 33924) * 256 + tid) >> 6;   // 0..2047
    int lane = tid & 63;
    int k = wid & (DK - 1); int h = wid >> 9;
    const float4* w4 = reinterpret_cast<const float4*>(Wq + (size_t)(h * DK + k) * DUNITS);
    float acc[BB];
#pragma unroll
    for (int b = 0; b < BB; ++b) acc[b] = 0.f;
#pragma unroll
    for (int j = 0; j < 4; ++j) {
      float4 ww = w4[j * 64 + lane];
#pragma unroll
      for (int b = 0; b < BB; ++b) {
        float4 a = reinterpret_cast<const float4*>(dec + (size_t)b * DUNITS)[j * 64 + lane];
        acc[b] += a.x * ww.x + a.y * ww.y + a.z * ww.z + a.w * ww.w;
      }
    }
#pragma unroll
    for (int off = 32; off; off >>= 1)
#pragma unroll
      for (int b = 0; b < BB; ++b) acc[b] += __shfl_xor(acc[b], off);
    if (lane == 0) {
      float bqv = bq[h * DK + k];
#pragma unroll
      for (int b = 0; b < BB; ++b) Qb[(h * BB + b) * DK + k] = acc[b] + bqv;
    }
  } else {
    int i = (bid - 34436) * 256 + tid;
    if (i < 65536) ctx[i] = 0.f;
  }
}

// ---------- fused e kernel (round-8 form: rolled loop + pointer rotation) ----------
// Tri-buffered LDS staging via global_load_lds; counted vmcnt before each barrier
// (keeps newest prefetches in flight, forces the consumed tile's staging complete).
// NOTE: VGPR must stay <= 64 (64 VGPR + 64 AGPR = 128 = 2 blocks/CU). Edits that
// add ~8 live regs (rounds 9/11) cross the 128 cliff -> 1 block/CU, -25%.
__global__ __launch_bounds__(512, 3) void e_kernel(const short* __restrict__ encb,
                                                   const short* __restrict__ Bp,
                                                   const float* __restrict__ S,
                                                   const float* __restrict__ Qb,
                                                   const float* __restrict__ gw,
                                                   const int* __restrict__ lens,
                                                   float* __restrict__ ebuf) {
  __shared__ short At[3][64 * 128];
  __shared__ float epart[8][64];

  int bid = blockIdx.x;
  int h = bid >> 9; int rem = bid & 511; int b = rem >> 5; int t0 = (rem & 31) << 6;
  int tid = threadIdx.x; int w = tid >> 6; int l = tid & 63;
  int lrow = l & 15, lhi = l >> 4;
  int len = lens[b];
  float invlen = 1.0f / (float)len;
  int af = (100 * (h + 1)) >> 2;

  const short* encB = encb + ((size_t)(b * TT + t0)) * EPROJS;
  const short* BpH = Bp + (size_t)h * 589824;

  // staging addresses: 2 chunks/thread, LDS chunk-linear (lane-contiguous per wave)
  int ci0 = tid, ci1 = 512 + tid;
  int r0 = ci0 >> 4, p0 = ci0 & 15;
  int r1 = ci1 >> 4, p1 = ci1 & 15;
  const short* g0 = encB + (size_t)r0 * EPROJS + ((p0 ^ (r0 & 7)) << 3);
  const short* g1 = encB + (size_t)r1 * EPROJS + ((p1 ^ (r1 & 7)) << 3);
  int d0 = ci0 * 8, d1 = ci1 * 8;   // LDS offsets in shorts
  int rx = lrow & 7;

  // B depth-1 prefetch: kkidx 0
  bf16x8 bnext[4];
#pragma unroll
  for (int n = 0; n < 4; ++n)
    bnext[n] = *reinterpret_cast<const bf16x8*>(BpH + (w * 4 + n) * 512 + l * 8);

  short* A0 = &At[0][0]; short* A1 = &At[1][0]; short* A2 = &At[2][0];

  // stage tiles 0 (buf0) and 1 (buf1)
  GLL16(g0, A0 + d0); GLL16(g1, A0 + d1);
  GLL16(g0 + 128, A1 + d0); GLL16(g1 + 128, A1 + d1);

  f32x4 acc[4][4] = {};

  __builtin_amdgcn_sched_barrier(0);
  asm volatile("s_waitcnt vmcnt(2)" ::: "memory");   // tile 0 complete; tile 1 in flight
  __builtin_amdgcn_s_barrier();
  __builtin_amdgcn_sched_barrier(0);

  const float* Sh = S + h * 202 * 128;

  for (int t = 0; t < 9; ++t) {
    if (t == 6) {
      // conv tile (tile 8) into buf2 == A2 at this rotation
      int srow = tid >> 3, sc = tid & 7;
      int tt = t0 + srow;
      int lo = af - tt; if (lo < 0) lo = 0;
      int hi = af - tt + len - 1; if (hi > 2 * af) hi = 2 * af;
      bool any = (hi >= lo);
      const float* Plo = Sh + lo * 128;
      const float* Phi = Sh + (hi + 1) * 128;
      short o0[8], o1[8];
#pragma unroll
      for (int e = 0; e < 8; ++e) {
        int c = sc * 8 + e;
        float v0 = any ? (Phi[c] - Plo[c]) * invlen : 0.f;
        float v1 = any ? (Phi[c + 64] - Plo[c + 64]) * invlen : 0.f;
        o0[e] = f2bf(v0); o1[e] = f2bf(v1);
      }
      *reinterpret_cast<bf16x8*>(&A2[srow * 128 + ((sc ^ (srow & 7)) << 3)]) =
          *reinterpret_cast<bf16x8*>(o0);
      *reinterpret_cast<bf16x8*>(&A2[srow * 128 + (((sc + 8) ^ (srow & 7)) << 3)]) =
          *reinterpret_cast<bf16x8*>(o1);
    }
#pragma unroll
    for (int kk = 0; kk < 4; ++kk) {
      bf16x8 bcur[4];
#pragma unroll
      for (int n = 0; n < 4; ++n) bcur[n] = bnext[n];
      int nk = t * 4 + kk + 1;
      if (nk < 36) {
        const short* bp = BpH + (size_t)nk * 16384 + l * 8;
#pragma unroll
        for (int n = 0; n < 4; ++n)
          bnext[n] = *reinterpret_cast<const bf16x8*>(bp + (w * 4 + n) * 512);
      }
      bf16x8 afr[4];
      int x = ((kk * 4 + lhi) ^ rx) << 3;
#pragma unroll
      for (int m = 0; m < 4; ++m)
        afr[m] = *reinterpret_cast<const bf16x8*>(&A0[(m * 16 + lrow) * 128 + x]);
#pragma unroll
      for (int m = 0; m < 4; ++m)
#pragma unroll
        for (int n = 0; n < 4; ++n)
          acc[m][n] = __builtin_amdgcn_mfma_f32_16x16x32_bf16(afr[m], bcur[n], acc[m][n], 0, 0, 0);
    }
    if (t < 6) {
      // stage tile t+2 into A2 (freed after iter t-1); issued AFTER this iter's B loads
      __builtin_amdgcn_sched_barrier(0);
      const short* gs0 = g0 + (t + 2) * 128;
      const short* gs1 = g1 + (t + 2) * 128;
      GLL16(gs0, A2 + d0); GLL16(gs1, A2 + d1);
    }
    __builtin_amdgcn_sched_barrier(0);
    if (t < 6) {
      // allow: 4 B-prefetch (kk=3) + 2 staging(t+2); forces staging(t+1) complete
      asm volatile("s_waitcnt vmcnt(6) lgkmcnt(0)" ::: "memory");
    } else {
      // no staging issued this iter; allow only the 4 B-prefetch loads
      asm volatile("s_waitcnt vmcnt(4) lgkmcnt(0)" ::: "memory");
    }
    __builtin_amdgcn_s_barrier();
    __builtin_amdgcn_sched_barrier(0);
    // rotate buffers: read buf advances
    short* tmp = A0; A0 = A1; A1 = A2; A2 = tmp;
  }

  // epilogue: tanh(pre + Q) * g_w, reduce over k
  float part[4][4];
#pragma unroll
  for (int m = 0; m < 4; ++m)
#pragma unroll
    for (int r = 0; r < 4; ++r) part[m][r] = 0.f;

#pragma unroll
  for (int n = 0; n < 4; ++n) {
    int col = w * 64 + n * 16 + lrow;
    float qv = Qb[(h * BB + b) * DK + col];
    float gv = gw[h * DK + col];
#pragma unroll
    for (int m = 0; m < 4; ++m)
#pragma unroll
      for (int r = 0; r < 4; ++r)
        part[m][r] += fast_tanh(acc[m][n][r] + qv) * gv;
  }
#pragma unroll
  for (int off = 1; off < 16; off <<= 1)
#pragma unroll
    for (int m = 0; m < 4; ++m)
#pragma unroll
      for (int r = 0; r < 4; ++r) part[m][r] += __shfl_xor(part[m][r], off);

  if (lrow == 0) {
#pragma unroll
    for (int m = 0; m < 4; ++m)
#pragma unroll
      for (int r = 0; r < 4; ++r) epart[w][m * 16 + lhi * 4 + r] = part[m][r];
  }
  __syncthreads();
  if (tid < 64) {
    float s = 0.f;
#pragma unroll
    for (int ww = 0; ww < 8; ++ww) s += epart[ww][tid];
    ebuf[(size_t)(h * BB + b) * TT + t0 + tid] = s;
  }
}

// ---------- masked softmax over t; writes ws region of d_out ----------
__global__ __launch_bounds__(256) void softmax_kernel(const float* __restrict__ ebuf,
                                                      const int* __restrict__ lens,
                                                      float* __restrict__ wout) {
  int hb = blockIdx.x; int b = hb & (BB - 1);
  int tid = threadIdx.x;
  int len = lens[b];
  const float scaling = 0.04419417382415922f;  // 1/sqrt(512)
  const float* er = ebuf + (size_t)hb * TT;
  float vals[8];
  float mx = -1e30f;
#pragma unroll
  for (int j = 0; j < 8; ++j) {
    int t = j * 256 + tid;
    float v = (t < len) ? scaling * er[t] : -1e30f;
    vals[j] = v; mx = fmaxf(mx, v);
  }
  __shared__ float red[256];
  red[tid] = mx; __syncthreads();
  for (int s2 = 128; s2; s2 >>= 1) { if (tid < s2) red[tid] = fmaxf(red[tid], red[tid + s2]); __syncthreads(); }
  mx = red[0]; __syncthreads();
  float sum = 0.f;
#pragma unroll
  for (int j = 0; j < 8; ++j) {
    int t = j * 256 + tid;
    vals[j] = (t < len) ? __expf(vals[j] - mx) : 0.f;
    sum += vals[j];
  }
  red[tid] = sum; __syncthreads();
  for (int s2 = 128; s2; s2 >>= 1) { if (tid < s2) red[tid] += red[tid + s2]; __syncthreads(); }
  float inv = 1.f / red[0];
#pragma unroll
  for (int j = 0; j < 8; ++j)
    wout[(size_t)hb * TT + j * 256 + tid] = vals[j] * inv;
}

// ---------- ctx[h][b][e] = sum_t w[h][b][t] * enc_bf16[b][t][e] (round-5 form) ----------
__global__ __launch_bounds__(256) void ctx_kernel(const short* __restrict__ encb,
                                                  const float* __restrict__ wout,
                                                  float* __restrict__ ctx) {
  int bid = blockIdx.x;                      // 16 * 4 * 8 = 512
  int tc = bid & 7; int ec = (bid >> 3) & 3; int b = bid >> 5;
  int tid = threadIdx.x;
  int ecol = ec * 256 + tid;
  int t0 = tc * 256;
  __shared__ float wls[4][256];
#pragma unroll
  for (int h = 0; h < 4; ++h) wls[h][tid] = wout[(size_t)(h * BB + b) * TT + t0 + tid];
  __syncthreads();
  float a0 = 0.f, a1 = 0.f, a2 = 0.f, a3 = 0.f;
  const short* ep = encb + ((size_t)(b * TT + t0)) * EPROJS + ecol;
  for (int t2 = 0; t2 < 256; ++t2) {
    float v = bf2f(ep[(size_t)t2 * EPROJS]);
    a0 += wls[0][t2] * v; a1 += wls[1][t2] * v; a2 += wls[2][t2] * v; a3 += wls[3][t2] * v;
  }
  atomicAdd(&ctx[(0 * BB + b) * EPROJS + ecol], a0);
  atomicAdd(&ctx[(1 * BB + b) * EPROJS + ecol], a1);
  atomicAdd(&ctx[(2 * BB + b) * EPROJS + ecol], a2);
  atomicAdd(&ctx[(3 * BB + b) * EPROJS + ecol], a3);
}

// ---------- cv[b][h*512+v] = ctx[h][b] . Wv[h][v] ; one wave per (h,v), all 16 b ----------
__global__ __launch_bounds__(256) void cv_kernel(const float* __restrict__ ctx,
                                                 const float* __restrict__ Wv,
                                                 float* __restrict__ cvb) {
  int wid = (blockIdx.x * blockDim.x + threadIdx.x) >> 6;   // 0..2047
  int lane = threadIdx.x & 63;
  int v = wid & (DV - 1); int h = wid >> 9;
  const float4* w4 = reinterpret_cast<const float4*>(Wv + (size_t)(h * DV + v) * EPROJS);
  float acc[BB];
#pragma unroll
  for (int b = 0; b < BB; ++b) acc[b] = 0.f;
#pragma unroll
  for (int j = 0; j < 4; ++j) {
    float4 ww = w4[j * 64 + lane];
#pragma unroll
    for (int b = 0; b < BB; ++b) {
      float4 a = reinterpret_cast<const float4*>(ctx + (size_t)(h * BB + b) * EPROJS)[j * 64 + lane];
      acc[b] += a.x * ww.x + a.y * ww.y + a.z * ww.z + a.w * ww.w;
    }
  }
#pragma unroll
  for (int off = 32; off; off >>= 1)
#pragma unroll
    for (int b = 0; b < BB; ++b) acc[b] += __shfl_xor(acc[b], off);
  if (lane == 0) {
#pragma unroll
    for (int b = 0; b < BB; ++b) cvb[b * 2048 + h * DV + v] = acc[b];
  }
}

// ---------- c[b][p] = cv[b] . Wo[p] ; one wave per p, all 16 b ----------
__global__ __launch_bounds__(256) void out_kernel(const float* __restrict__ cvb,
                                                  const float* __restrict__ Wo,
                                                  float* __restrict__ outc) {
  int p = (blockIdx.x * blockDim.x + threadIdx.x) >> 6;   // 0..1023
  int lane = threadIdx.x & 63;
  const float4* w4 = reinterpret_cast<const float4*>(Wo + (size_t)p * 2048);
  float acc[BB];
#pragma unroll
  for (int b = 0; b < BB; ++b) acc[b] = 0.f;
#pragma unroll
  for (int j = 0; j < 8; ++j) {
    float4 ww = w4[j * 64 + lane];
#pragma unroll
    for (int b = 0; b < BB; ++b) {
      float4 a = reinterpret_cast<const float4*>(cvb + (size_t)b * 2048)[j * 64 + lane];
      acc[b] += a.x * ww.x + a.y * ww.y + a.z * ww.z + a.w * ww.w;
    }
  }
#pragma unroll
  for (int off = 32; off; off >>= 1)
#pragma unroll
    for (int b = 0; b < BB; ++b) acc[b] += __shfl_xor(acc[b], off);
  if (lane == 0) {
#pragma unroll
    for (int b = 0; b < BB; ++b) outc[b * 1024 + p] = acc[b];
  }
}

extern "C" void kernel_launch(void* const* d_in, const int* in_sizes, int n_in,
                              void* d_out, int out_size, void* d_ws, size_t ws_size,
                              hipStream_t stream) {
  const float* enc  = (const float*)d_in[0];
  const int*   lens = (const int*)d_in[1];
  const float* dec  = (const float*)d_in[2];
  const float* Wq   = (const float*)d_in[3];
  const float* bq   = (const float*)d_in[4];
  const float* Wk   = (const float*)d_in[5];
  const float* Wv   = (const float*)d_in[6];
  const float* gw   = (const float*)d_in[7];
  const float* Watt = (const float*)d_in[9];
  const float* cw0  = (const float*)d_in[10];
  const float* cw1  = (const float*)d_in[11];
  const float* cw2  = (const float*)d_in[12];
  const float* cw3  = (const float*)d_in[13];
  const float* Wo   = (const float*)d_in[14];
  float* out = (float*)d_out;

  char* ws = (char*)d_ws;
  short* Bp    = (short*)(ws);                 // 4,718,592 B
  float* S     = (float*)(ws + 4718592);       // 413,696 B
  float* Qb    = (float*)(ws + 5132288);       // 131,072 B
  float* ebuf  = (float*)(ws + 5263360);       // 524,288 B
  float* ctx   = (float*)(ws + 6311936);       // 262,144 B
  float* cvb   = (float*)(ws + 6574080);       // 131,072 B
  short* encb  = (short*)(ws + 6815744);       // 67,108,864 B

  float* wsout = out + 16384;                  // ws output region (4,16,2048)

  prep_kernel<<<34692, 256, 0, stream>>>(enc, encb, Wk, Watt, Bp,
                                         cw0, cw1, cw2, cw3, S,
                                         dec, Wq, bq, Qb, ctx);
  e_kernel<<<2048, 512, 0, stream>>>(encb, Bp, S, Qb, gw, lens, ebuf);
  softmax_kernel<<<64, 256, 0, stream>>>(ebuf, lens, wsout);
  ctx_kernel<<<512, 256, 0, stream>>>(encb, wsout, ctx);
  cv_kernel<<<512, 256, 0, stream>>>(ctx, Wv, cvb);
  out_kernel<<<256, 256, 0, stream>>>(cvb, Wo, out);
}